// Round 4
// baseline (29.398 us; speedup 1.0000x reference)
//
#include <hip/hip_runtime.h>

// ColorReducer: per-pixel argmin_k of d2 = (x2 - 2.0f*cross) + p2 with the
// EXACT verified expression tree (R0/R2 passed with absmax 0.0):
//   cross = ((r*pr + g*pg) + b*pb), x2 = ((r*r + g*g) + b*b),
//   d2 = (x2 - 2.0f*cross) + p2, +inf seed, strict < (np.argmin tie-break).
// DO NOT touch the math (R1 changed the tree and flipped labels).
//
// R3: structural change only — grid-stride register-double-buffered pipeline
// to break the whole-grid load/compute/store convoy (R0/R2 ~26-28 us ==
// 8 us load burst + 10 us VALU + 8 us store tail, serialized):
//   1024 blocks x 256 thr, 4 iters/thread x 4 px/iter.
//   load(0); for j: { issue loads(j+1); compute+store(j); }  (named bufs)

constexpr int HW     = 512 * 512;          // 2^18
constexpr int KCOL   = 16;
constexpr long NPIX  = 16L * HW;           // 4,194,304
constexpr int PPI    = 4;                  // pixels per iteration (float4)
constexpr int NITER  = 4;
constexpr int THREADS = 256;
constexpr int BLOCKS = (int)(NPIX / ((long)PPI * NITER * THREADS));  // 1024
constexpr int SWEEP  = BLOCKS * THREADS * PPI;                       // 1,048,576

__device__ __forceinline__ void load4(const float* __restrict__ x, int p,
                                      float4& rv, float4& gv, float4& bv)
{
    const int b   = p >> 18;
    const int pix = p & (HW - 1);
    const float* base = x + (size_t)b * 3 * HW + pix;
    rv = *reinterpret_cast<const float4*>(base);
    gv = *reinterpret_cast<const float4*>(base + HW);
    bv = *reinterpret_cast<const float4*>(base + 2 * HW);
}

__device__ __forceinline__ void compute_store4(
    const float4 rv, const float4 gv, const float4 bv,
    const float* __restrict__ pal,      // uniform -> SGPRs
    const float* spal,                  // LDS palette for the gather
    float* __restrict__ out, int p)
{
    float r[4]  = {rv.x, rv.y, rv.z, rv.w};
    float g[4]  = {gv.x, gv.y, gv.z, gv.w};
    float bl[4] = {bv.x, bv.y, bv.z, bv.w};

    float x2[4], best[4];
    int bestk[4];
#pragma unroll
    for (int i = 0; i < 4; ++i) {
        x2[i] = __fadd_rn(__fadd_rn(__fmul_rn(r[i], r[i]),
                                    __fmul_rn(g[i], g[i])),
                          __fmul_rn(bl[i], bl[i]));
        best[i]  = 3.4e38f;
        bestk[i] = 0;
    }

#pragma unroll
    for (int k = 0; k < KCOL; ++k) {
        const float pr = pal[3 * k + 0];
        const float pg = pal[3 * k + 1];
        const float pb = pal[3 * k + 2];
        const float p2 = __fadd_rn(__fadd_rn(__fmul_rn(pr, pr),
                                             __fmul_rn(pg, pg)),
                                   __fmul_rn(pb, pb));
#pragma unroll
        for (int i = 0; i < 4; ++i) {
            const float cross = __fadd_rn(__fadd_rn(__fmul_rn(r[i], pr),
                                                    __fmul_rn(g[i], pg)),
                                          __fmul_rn(bl[i], pb));
            const float d2 = __fadd_rn(__fsub_rn(x2[i], __fmul_rn(2.0f, cross)),
                                       p2);
            if (d2 < best[i]) { best[i] = d2; bestk[i] = k; }  // strict <
        }
    }

    float orr[4], ogg[4], obb[4];
#pragma unroll
    for (int i = 0; i < 4; ++i) {
        orr[i] = spal[3 * bestk[i] + 0];
        ogg[i] = spal[3 * bestk[i] + 1];
        obb[i] = spal[3 * bestk[i] + 2];
    }

    const int b   = p >> 18;
    const int pix = p & (HW - 1);
    float* ob = out + (size_t)b * 3 * HW + pix;
    *reinterpret_cast<float4*>(ob)          = make_float4(orr[0], orr[1], orr[2], orr[3]);
    *reinterpret_cast<float4*>(ob + HW)     = make_float4(ogg[0], ogg[1], ogg[2], ogg[3]);
    *reinterpret_cast<float4*>(ob + 2 * HW) = make_float4(obb[0], obb[1], obb[2], obb[3]);
}

__global__ __launch_bounds__(THREADS) void color_reduce_kernel(
    const float* __restrict__ x,       // (B, 3, H, W)
    const float* __restrict__ pal,     // (16, 3)
    float* __restrict__ out)           // (B, 3, H, W)
{
    __shared__ float spal[KCOL * 3];
    if (threadIdx.x < KCOL * 3) spal[threadIdx.x] = pal[threadIdx.x];
    __syncthreads();

    const int t4 = (blockIdx.x * THREADS + threadIdx.x) * PPI;

    // Register double-buffered pipeline over 4 contiguous sweeps.
    float4 rA, gA, bA, rB, gB, bB;

    load4(x, 0 * SWEEP + t4, rA, gA, bA);                 // prologue

    load4(x, 1 * SWEEP + t4, rB, gB, bB);                 // prefetch j=1
    compute_store4(rA, gA, bA, pal, spal, out, 0 * SWEEP + t4);

    load4(x, 2 * SWEEP + t4, rA, gA, bA);                 // prefetch j=2
    compute_store4(rB, gB, bB, pal, spal, out, 1 * SWEEP + t4);

    load4(x, 3 * SWEEP + t4, rB, gB, bB);                 // prefetch j=3
    compute_store4(rA, gA, bA, pal, spal, out, 2 * SWEEP + t4);

    compute_store4(rB, gB, bB, pal, spal, out, 3 * SWEEP + t4);  // drain
}

extern "C" void kernel_launch(void* const* d_in, const int* in_sizes, int n_in,
                              void* d_out, int out_size, void* d_ws, size_t ws_size,
                              hipStream_t stream) {
    const float* x   = (const float*)d_in[0];
    const float* pal = (const float*)d_in[1];
    float* out       = (float*)d_out;

    color_reduce_kernel<<<BLOCKS, THREADS, 0, stream>>>(x, pal, out);
}